// Round 7
// baseline (282.714 us; speedup 1.0000x reference)
//
#include <hip/hip_runtime.h>
#include <math.h>

#define NPTS 4096
#define EIG  512        // candidates per wave (8 waves x 512 = 4096)
#define KNN  16
#define H_DIM 128
#define HID1 64
#define A_DIM 32
#define G_DIM 16

#define BUF_ROWS 7      // scan buffer rows (max write index 6: cnt<=3 after check, +4)
#define FLUSH_AT 4
#define GROUP 4
#define EPS 3e-4f       // covers |fma-surrogate - exact-rn d2| (~1e-5) with margin

typedef unsigned long long u64;
typedef unsigned short u16;

// key = (f32 bits of d2) << 32 | j.  d2 >= 0 -> u64 ascending == (d2 asc, j asc)
// == jax.lax.top_k's stable lowest-index-tie-break order.

#define SWAP_ST(k)                                                         \
    { bool sw_ = best[k] < best[k-1];                                      \
      u64 lo_ = sw_ ? best[k] : best[k-1];                                 \
      u64 hi_ = sw_ ? best[k-1] : best[k];                                 \
      best[k-1] = lo_; best[k] = hi_; }

#define INSERT_KEY(keyv)                                                   \
    { best[15] = (keyv);                                                   \
      SWAP_ST(15) SWAP_ST(14) SWAP_ST(13) SWAP_ST(12) SWAP_ST(11)          \
      SWAP_ST(10) SWAP_ST(9)  SWAP_ST(8)  SWAP_ST(7)  SWAP_ST(6)           \
      SWAP_ST(5)  SWAP_ST(4)  SWAP_ST(3)  SWAP_ST(2)  SWAP_ST(1) }

#define CE(i, j)                                                           \
    { u64 x_ = m[i], y_ = m[j];                                            \
      bool sw_ = y_ < x_;                                                  \
      m[i] = sw_ ? y_ : x_; m[j] = sw_ ? x_ : y_; }

__global__ __launch_bounds__(512, 4) void knn_film_mlp_kernel(
    const float* __restrict__ pos, const float* __restrict__ goal,
    const float* __restrict__ W1, const float* __restrict__ b1,
    const float* __restrict__ W2, const float* __restrict__ b2,
    const float* __restrict__ Wg, const float* __restrict__ bg,
    const float* __restrict__ Wb, const float* __restrict__ bb,
    const float* __restrict__ Wa, const float* __restrict__ ba,
    float* __restrict__ out)
{
    // pool (12544 B), phase-aliased:
    //   scan phase : [0,7168)  u16 scanbuf[7][512];  [12288,12544) int sthr[64]
    //   merge phase: slot s at byte s*6144: f32 d2[16][64] then u16 idx[16][64]
    __shared__ float4 sp[NPTS];             // 64 KB; reused as MLP partials
    __shared__ int    pool[12544 / 4];      // 12.25 KB
    __shared__ float  gam[H_DIM], bet[H_DIM];
    __shared__ float  lcx[64], lcy[64], lcz[64];

    const int tid  = threadIdx.x;
    const int lane = tid & 63;
    const int wid  = tid >> 6;              // 8 waves own candidate eighths
    const int b     = blockIdx.x >> 6;
    const int chunk = blockIdx.x & 63;
    const int q     = chunk * 64 + lane;    // all waves share the same 64 queries

    u16* sbuf = (u16*)pool;                 // [7][512]
    int* sthr = pool + (12288 / 4);         // [64] f32-as-int, lane-indexed

    if (tid < 64) sthr[tid] = 0x7F800000;   // +inf bits

    // ---- stage points: sq = ((x*x + y*y) + z*z), per-op rounding == numpy ----
    const float* pb = pos + (size_t)b * NPTS * 3;
    for (int j = tid; j < NPTS; j += 512) {
        float x = pb[j * 3 + 0];
        float y = pb[j * 3 + 1];
        float z = pb[j * 3 + 2];
        float sq = __fadd_rn(__fadd_rn(__fmul_rn(x, x), __fmul_rn(y, y)),
                             __fmul_rn(z, z));
        sp[j] = make_float4(x, y, z, sq);
    }
    if (tid < H_DIM) {
        const float* gl = goal + b * G_DIM;
        float sg = bg[tid];
        float sb = bb[tid];
        #pragma unroll
        for (int g = 0; g < G_DIM; ++g) {
            float gv = gl[g];
            sg = fmaf(gv, Wg[g * H_DIM + tid], sg);
            sb = fmaf(gv, Wb[g * H_DIM + tid], sb);
        }
        gam[tid] = sg;
        bet[tid] = sb;
    }
    __syncthreads();                        // B1

    const float4 me = sp[q];
    const float nx = -2.0f * me.x, ny = -2.0f * me.y, nz = -2.0f * me.z;

    // exact d2, numpy association: ((xx'+yy')+zz'); (sqi+sqj)-2*dot
#define CAND_D2(c)                                                             \
    __fsub_rn(__fadd_rn(me.w, (c).w),                                          \
              __fmul_rn(2.0f,                                                  \
                        __fadd_rn(__fadd_rn(__fmul_rn(me.x, (c).x),            \
                                            __fmul_rn(me.y, (c).y)),           \
                                  __fmul_rn(me.z, (c).z))))

    u64 best[KNN];
    #pragma unroll
    for (int k = 0; k < KNN; ++k) best[k] = 0xFFFFFFFFFFFFFFFFull;

    const int jbase = wid * EIG;

    // ---- warmup: 16 unconditional exact inserts seed local list + shared thr ----
    for (int j = jbase; j < jbase + KNN; ++j) {
        float4 c = sp[j];
        float d2 = fmaxf(CAND_D2(c), 0.0f);
        u64 key = ((u64)__float_as_uint(d2) << 32) | (unsigned)j;
        INSERT_KEY(key);
    }
    atomicMin(&sthr[lane], (int)(unsigned)(best[15] >> 32));

    int cnt = 0;

    // FLUSH: exact-recheck buffered j's; then tighten the shared threshold
#define FLUSH()                                                                \
    { int t = 0;                                                               \
      while (__any(t < cnt)) {                                                 \
          int j = sbuf[t * 512 + tid] & (NPTS - 1);                            \
          float4 c = sp[j];                                                    \
          float d2 = fmaxf(CAND_D2(c), 0.0f);                                  \
          u64 key = ((u64)__float_as_uint(d2) << 32) | (unsigned)j;            \
          if ((t < cnt) && (key < best[15])) { INSERT_KEY(key); }              \
          t++;                                                                 \
      }                                                                        \
      cnt = 0;                                                                 \
      unsigned b15_ = (unsigned)(best[15] >> 32);                              \
      if (b15_ < 0x7F800000u) atomicMin(&sthr[lane], (int)b15_); }

    // ---- main scan: shared-thr surrogate filter + lean append ----
    // Safety: sthr[l] is min over waves' local 16th-d2 >= global 16th-d2, so
    // filtering with it never drops a global-top-16 member; exact u64 keys at
    // flush + (range top16 superset) argument keep the final set bit-exact.
    for (int j0 = jbase + KNN; j0 < jbase + EIG; j0 += GROUP) {
        float sv = __int_as_float(sthr[lane]);
        float tm = (sv - me.w) + EPS;
        #pragma unroll
        for (int jj = 0; jj < GROUP; ++jj) {
            const int j = j0 + jj;
            float4 c = sp[j];
            float s = fmaf(nx, c.x, fmaf(ny, c.y, fmaf(nz, c.z, c.w)));
            bool pass = s < tm;             // no false negatives (EPS bound)
            sbuf[cnt * 512 + tid] = (u16)j; // unconditional append slot
            cnt += pass ? 1 : 0;
        }
        if (__any(cnt >= FLUSH_AT)) FLUSH();
    }
    FLUSH();                                // final drain

    // ---- merge 8 sorted lists: pipelined 2-slot chain, wave0 accumulates ----
#define PUBLISH(s)                                                             \
    _Pragma("unroll")                                                          \
    for (int k = 0; k < KNN; ++k) {                                            \
        ((float*)pool)[(s) * 1536 + k * 64 + lane] =                           \
            __uint_as_float((unsigned)(best[k] >> 32));                        \
        ((u16*)pool)[(s) * 3072 + 2048 + k * 64 + lane] =                      \
            (u16)(best[k] & 0xFFFFu);                                          \
    }

#define MERGE_FROM(s)                                                          \
    { u64 m[16];                                                               \
      _Pragma("unroll")                                                        \
      for (int i = 0; i < 16; ++i) {                                           \
          int kk = 15 - i;                                                     \
          u64 bk = ((u64)__float_as_uint(                                      \
                        ((float*)pool)[(s) * 1536 + kk * 64 + lane]) << 32)    \
                 | (u64)((u16*)pool)[(s) * 3072 + 2048 + kk * 64 + lane];      \
          m[i] = best[i] < bk ? best[i] : bk;                                  \
      }                                                                        \
      CE(0,8) CE(1,9) CE(2,10) CE(3,11) CE(4,12) CE(5,13) CE(6,14) CE(7,15)    \
      CE(0,4) CE(1,5) CE(2,6) CE(3,7) CE(8,12) CE(9,13) CE(10,14) CE(11,15)    \
      CE(0,2) CE(1,3) CE(4,6) CE(5,7) CE(8,10) CE(9,11) CE(12,14) CE(13,15)    \
      CE(0,1) CE(2,3) CE(4,5) CE(6,7) CE(8,9) CE(10,11) CE(12,13) CE(14,15)    \
      _Pragma("unroll")                                                        \
      for (int i = 0; i < 16; ++i) best[i] = m[i]; }

    __syncthreads();                        // B2: scanbuf dead, slots usable
    if (wid == 1) PUBLISH(0);
    if (wid == 2) PUBLISH(1);
    __syncthreads();
    if (wid == 0) MERGE_FROM(0);
    __syncthreads();
    if (wid == 0) MERGE_FROM(1);
    if (wid == 3) PUBLISH(0);
    __syncthreads();
    if (wid == 0) MERGE_FROM(0);
    if (wid == 4) PUBLISH(1);
    __syncthreads();
    if (wid == 0) MERGE_FROM(1);
    if (wid == 5) PUBLISH(0);
    __syncthreads();
    if (wid == 0) MERGE_FROM(0);
    if (wid == 6) PUBLISH(1);
    __syncthreads();
    if (wid == 0) MERGE_FROM(1);
    if (wid == 7) PUBLISH(0);
    __syncthreads();
    if (wid == 0) {
        MERGE_FROM(0);                      // final global top-16, sorted
        float sx = 0.0f, sy = 0.0f, sz = 0.0f;
        #pragma unroll
        for (int k = 0; k < KNN; ++k) {     // ascending-(d2,idx) order
            float4 nb = sp[(unsigned)(best[k] & 0xFFFFu)];
            sx += nb.x; sy += nb.y; sz += nb.z;
        }
        const float inv = 1.0f / (float)KNN;
        lcx[lane] = sx * inv - me.x;
        lcy[lane] = sy * inv - me.y;
        lcz[lane] = sz * inv - me.z;
    }
    __syncthreads();                        // lc ready; sp dead -> partials

    // ---- MLP, all 8 waves: wave w handles channels [w*16, w*16+16) ----
    {
        const float x3 = lcx[lane], x4 = lcy[lane], x5 = lcz[lane];
        float h[HID1];
        #pragma unroll
        for (int c = 0; c < HID1; ++c) {
            float a = b1[c];
            a = fmaf(me.x, W1[0 * HID1 + c], a);
            a = fmaf(me.y, W1[1 * HID1 + c], a);
            a = fmaf(me.z, W1[2 * HID1 + c], a);
            a = fmaf(x3,   W1[3 * HID1 + c], a);
            a = fmaf(x4,   W1[4 * HID1 + c], a);
            a = fmaf(x5,   W1[5 * HID1 + c], a);
            h[c] = fmaxf(a, 0.0f);
        }
        float acc[A_DIM];
        #pragma unroll
        for (int a = 0; a < A_DIM; ++a) acc[a] = 0.0f;
        const int c0 = wid * 16;            // uniform per wave
        #pragma unroll 4
        for (int cc = 0; cc < 16; ++cc) {
            const int c = c0 + cc;
            float s = b2[c];
            #pragma unroll
            for (int k = 0; k < HID1; ++k) s = fmaf(h[k], W2[k * H_DIM + c], s);
            float f = fmaf(gam[c], fmaxf(s, 0.0f), bet[c]);
            const float* wac = Wa + c * A_DIM;
            #pragma unroll
            for (int a = 0; a < A_DIM; ++a) acc[a] = fmaf(f, wac[a], acc[a]);
        }
        float* P = (float*)sp;              // [(w*32+a)*64 + lane], conflict-free
        #pragma unroll
        for (int a = 0; a < A_DIM; ++a) P[(wid * A_DIM + a) * 64 + lane] = acc[a];
    }
    __syncthreads();

    // ---- reduce 8 partials + bias + relu; float4 stores ----
    {
        const float* P = (const float*)sp;
        const int qi = tid & 63;
        const int a0 = (tid >> 6) * 4;
        float o[4];
        #pragma unroll
        for (int i = 0; i < 4; ++i) {
            float ssum = ba[a0 + i];
            #pragma unroll
            for (int w = 0; w < 8; ++w)
                ssum += P[(w * A_DIM + a0 + i) * 64 + qi];
            o[i] = fmaxf(ssum, 0.0f);
        }
        float4* op4 = (float4*)(out + ((size_t)b * NPTS + chunk * 64 + qi) * A_DIM + a0);
        *op4 = make_float4(o[0], o[1], o[2], o[3]);
    }
#undef CAND_D2
#undef FLUSH
#undef PUBLISH
#undef MERGE_FROM
}

extern "C" void kernel_launch(void* const* d_in, const int* in_sizes, int n_in,
                              void* d_out, int out_size, void* d_ws, size_t ws_size,
                              hipStream_t stream) {
    const float* pos  = (const float*)d_in[0];
    const float* goal = (const float*)d_in[1];
    const float* W1   = (const float*)d_in[2];
    const float* b1   = (const float*)d_in[3];
    const float* W2   = (const float*)d_in[4];
    const float* b2   = (const float*)d_in[5];
    const float* Wg   = (const float*)d_in[6];
    const float* bg   = (const float*)d_in[7];
    const float* Wb   = (const float*)d_in[8];
    const float* bb   = (const float*)d_in[9];
    const float* Wa   = (const float*)d_in[10];
    const float* ba   = (const float*)d_in[11];
    float* out = (float*)d_out;

    const int B = in_sizes[0] / (NPTS * 3);
    dim3 grid(B * 64);
    dim3 block(512);
    hipLaunchKernelGGL(knn_film_mlp_kernel, grid, block, 0, stream,
                       pos, goal, W1, b1, W2, b2, Wg, bg, Wb, bb, Wa, ba, out);
}

// Round 9
// 271.145 us; speedup vs baseline: 1.0427x; 1.0427x over previous
//
#include <hip/hip_runtime.h>
#include <math.h>

#define NPTS 4096
#define QTR  1024       // candidates per wave (4 waves x 1024)
#define KNN  16
#define H_DIM 128
#define HID1 64
#define A_DIM 32
#define G_DIM 16

#define WARMUP 16
#define WSZ 16          // scan window (16 candidates per mask)
#define NWIN ((QTR - WARMUP) / WSZ)   // 63
#define EPS 3e-4f       // covers |fma-surrogate - exact-rn d2| with wide margin

typedef unsigned long long u64;
typedef unsigned short u16;

// key = (f32 bits of d2) << 32 | j.  d2 >= 0 -> u64 ascending == (d2 asc, j asc)
// == jax.lax.top_k's stable lowest-index-tie-break order.

#define SWAP_ST(k)                                                         \
    { bool sw_ = best[k] < best[k-1];                                      \
      u64 lo_ = sw_ ? best[k] : best[k-1];                                 \
      u64 hi_ = sw_ ? best[k-1] : best[k];                                 \
      best[k-1] = lo_; best[k] = hi_; }

#define INSERT_KEY(keyv)                                                   \
    { best[15] = (keyv);                                                   \
      SWAP_ST(15) SWAP_ST(14) SWAP_ST(13) SWAP_ST(12) SWAP_ST(11)          \
      SWAP_ST(10) SWAP_ST(9)  SWAP_ST(8)  SWAP_ST(7)  SWAP_ST(6)           \
      SWAP_ST(5)  SWAP_ST(4)  SWAP_ST(3)  SWAP_ST(2)  SWAP_ST(1) }

#define CE(i, j)                                                           \
    { u64 x_ = m[i], y_ = m[j];                                            \
      bool sw_ = y_ < x_;                                                  \
      m[i] = sw_ ? y_ : x_; m[j] = sw_ ? x_ : y_; }

__global__ __launch_bounds__(256, 2) void knn_film_mlp_kernel(
    const float* __restrict__ pos, const float* __restrict__ goal,
    const float* __restrict__ W1, const float* __restrict__ b1,
    const float* __restrict__ W2, const float* __restrict__ b2,
    const float* __restrict__ Wg, const float* __restrict__ bg,
    const float* __restrict__ Wb, const float* __restrict__ bb,
    const float* __restrict__ Wa, const float* __restrict__ ba,
    float* __restrict__ out)
{
    __shared__ float4 sp[NPTS];             // 64 KB; reused as MLP partials
    __shared__ float  pubd[2][KNN][64];     // 8 KB merge slots (d2)
    __shared__ u16    pubi[2][KNN][64];     // 2 KB merge slots (idx)
    __shared__ float  gam[H_DIM], bet[H_DIM];
    __shared__ float  lcx[64], lcy[64], lcz[64];
    __shared__ int    sthr[64];             // shared per-query threshold (f32 bits)

    const int tid  = threadIdx.x;
    const int lane = tid & 63;
    const int wid  = tid >> 6;              // 4 waves own candidate quarters
    const int b     = blockIdx.x >> 6;
    const int chunk = blockIdx.x & 63;
    const int q     = chunk * 64 + lane;

    if (tid < 64) sthr[tid] = 0x7F800000;   // +inf bits

    // ---- stage points: sq = ((x*x + y*y) + z*z), per-op rounding == numpy ----
    const float* pb = pos + (size_t)b * NPTS * 3;
    for (int j = tid; j < NPTS; j += 256) {
        float x = pb[j * 3 + 0];
        float y = pb[j * 3 + 1];
        float z = pb[j * 3 + 2];
        float sq = __fadd_rn(__fadd_rn(__fmul_rn(x, x), __fmul_rn(y, y)),
                             __fmul_rn(z, z));
        sp[j] = make_float4(x, y, z, sq);
    }
    if (tid < H_DIM) {
        const float* gl = goal + b * G_DIM;
        float sg = bg[tid];
        float sb = bb[tid];
        #pragma unroll
        for (int g = 0; g < G_DIM; ++g) {
            float gv = gl[g];
            sg = fmaf(gv, Wg[g * H_DIM + tid], sg);
            sb = fmaf(gv, Wb[g * H_DIM + tid], sb);
        }
        gam[tid] = sg;
        bet[tid] = sb;
    }
    __syncthreads();                        // B1

    const float4 me = sp[q];
    const float nx = -2.0f * me.x, ny = -2.0f * me.y, nz = -2.0f * me.z;

    // exact d2, numpy association: ((xx'+yy')+zz'); (sqi+sqj)-2*dot
#define CAND_D2(c)                                                             \
    __fsub_rn(__fadd_rn(me.w, (c).w),                                          \
              __fmul_rn(2.0f,                                                  \
                        __fadd_rn(__fadd_rn(__fmul_rn(me.x, (c).x),            \
                                            __fmul_rn(me.y, (c).y)),           \
                                  __fmul_rn(me.z, (c).z))))

    u64 best[KNN];
    #pragma unroll
    for (int k = 0; k < KNN; ++k) best[k] = 0xFFFFFFFFFFFFFFFFull;

    const int jbase = wid * QTR;

    // ---- warmup: 16 unconditional exact inserts seed local list + shared thr ----
    for (int j = jbase; j < jbase + WARMUP; ++j) {
        float4 c = sp[j];
        float d2 = fmaxf(CAND_D2(c), 0.0f);
        u64 key = ((u64)__float_as_uint(d2) << 32) | (unsigned)j;
        INSERT_KEY(key);
    }
    atomicMin(&sthr[lane], (int)(unsigned)(best[15] >> 32));

    // ---- main scan: 16-candidate windows, bitmask filter, no scan buffer ----
    // Safety: sthr[l] = min over waves of local 16th-d2 >= global 16th-d2, so
    // the surrogate filter (error << EPS) never drops a global-top-16 member;
    // exact rn-sequence d2 + u64 keys at flush keep the final set bit-exact.
    for (int w = 0; w < NWIN; ++w) {
        const int wbase = jbase + WARMUP + w * WSZ;
        const float tm = (__int_as_float(sthr[lane]) - me.w) + EPS;
        unsigned mask = 0u;
        #pragma unroll
        for (int u = 0; u < WSZ; ++u) {
            float4 c = sp[wbase + u];       // wave-uniform addr -> LDS broadcast
            float s = fmaf(nx, c.x, fmaf(ny, c.y, fmaf(nz, c.z, c.w)));
            if (s < tm) mask |= (1u << u);
        }
        if (__any(mask != 0u)) {
            while (__any(mask != 0u)) {
                bool act = (mask != 0u);
                int bit = __ffs(mask) - 1;          // -1 when inactive
                mask &= mask - 1;
                int j = (wbase + bit) & (NPTS - 1); // safe addr for idle lanes
                float4 c = sp[j];
                float d2 = fmaxf(CAND_D2(c), 0.0f);
                u64 key = ((u64)__float_as_uint(d2) << 32) | (unsigned)j;
                if (act && key < best[15]) { INSERT_KEY(key); }
            }
            unsigned b15 = (unsigned)(best[15] >> 32);
            if (b15 < 0x7F800000u) atomicMin(&sthr[lane], (int)b15);
        }
    }

    // ---- cross-wave merge tree: (0<-2, 1<-3) then (0<-1); all-static ----
#define PUBLISH(s)                                                             \
    _Pragma("unroll")                                                          \
    for (int k = 0; k < KNN; ++k) {                                            \
        pubd[s][k][lane] = __uint_as_float((unsigned)(best[k] >> 32));         \
        pubi[s][k][lane] = (u16)(best[k] & 0xFFFFu);                           \
    }

#define MERGE_FROM(s)                                                          \
    { u64 m[16];                                                               \
      _Pragma("unroll")                                                        \
      for (int i = 0; i < 16; ++i) {                                           \
          int kk = 15 - i;                                                     \
          u64 bk = ((u64)__float_as_uint(pubd[s][kk][lane]) << 32)             \
                 | (u64)pubi[s][kk][lane];                                     \
          m[i] = best[i] < bk ? best[i] : bk;                                  \
      }                                                                        \
      CE(0,8) CE(1,9) CE(2,10) CE(3,11) CE(4,12) CE(5,13) CE(6,14) CE(7,15)    \
      CE(0,4) CE(1,5) CE(2,6) CE(3,7) CE(8,12) CE(9,13) CE(10,14) CE(11,15)    \
      CE(0,2) CE(1,3) CE(4,6) CE(5,7) CE(8,10) CE(9,11) CE(12,14) CE(13,15)    \
      CE(0,1) CE(2,3) CE(4,5) CE(6,7) CE(8,9) CE(10,11) CE(12,13) CE(14,15)    \
      _Pragma("unroll")                                                        \
      for (int i = 0; i < 16; ++i) best[i] = m[i]; }

    __syncthreads();                        // B2
    if (wid >= 2) PUBLISH(wid - 2);
    __syncthreads();                        // B3
    if (wid == 0) MERGE_FROM(0);
    if (wid == 1) { MERGE_FROM(1); PUBLISH(1); }
    __syncthreads();                        // B4
    if (wid == 0) {
        MERGE_FROM(1);                      // final global top-16, sorted
        float sx = 0.0f, sy = 0.0f, sz = 0.0f;
        #pragma unroll
        for (int k = 0; k < KNN; ++k) {     // ascending-(d2,idx) order == ref
            float4 nb = sp[(unsigned)(best[k] & 0xFFFFu)];
            sx += nb.x; sy += nb.y; sz += nb.z;
        }
        const float inv = 1.0f / (float)KNN;
        lcx[lane] = sx * inv - me.x;
        lcy[lane] = sy * inv - me.y;
        lcz[lane] = sz * inv - me.z;
    }
    __syncthreads();                        // B5: lc ready; sp dead -> partials

    // ---- MLP, all 4 waves: wave w handles channels [w*32, w*32+32) ----
    {
        const float x3 = lcx[lane], x4 = lcy[lane], x5 = lcz[lane];
        float h[HID1];
        #pragma unroll
        for (int c = 0; c < HID1; ++c) {
            float a = b1[c];
            a = fmaf(me.x, W1[0 * HID1 + c], a);
            a = fmaf(me.y, W1[1 * HID1 + c], a);
            a = fmaf(me.z, W1[2 * HID1 + c], a);
            a = fmaf(x3,   W1[3 * HID1 + c], a);
            a = fmaf(x4,   W1[4 * HID1 + c], a);
            a = fmaf(x5,   W1[5 * HID1 + c], a);
            h[c] = fmaxf(a, 0.0f);
        }
        float acc[A_DIM];
        #pragma unroll
        for (int a = 0; a < A_DIM; ++a) acc[a] = 0.0f;
        const int c0 = wid * 32;            // uniform per wave
        #pragma unroll 4
        for (int cc = 0; cc < 32; ++cc) {
            const int c = c0 + cc;
            float s = b2[c];
            #pragma unroll
            for (int k = 0; k < HID1; ++k) s = fmaf(h[k], W2[k * H_DIM + c], s);
            float f = fmaf(gam[c], fmaxf(s, 0.0f), bet[c]);
            const float* wac = Wa + c * A_DIM;
            #pragma unroll
            for (int a = 0; a < A_DIM; ++a) acc[a] = fmaf(f, wac[a], acc[a]);
        }
        float* P = (float*)sp;              // [(w*32+a)*64 + lane], conflict-free
        #pragma unroll
        for (int a = 0; a < A_DIM; ++a) P[(wid * A_DIM + a) * 64 + lane] = acc[a];
    }
    __syncthreads();                        // B6

    // ---- reduce partials + bias + relu; fully-coalesced float4 stores ----
    {
        const float* P = (const float*)sp;
        const int qi = tid >> 2, a0 = (tid & 3) * 8;
        float o[8];
        #pragma unroll
        for (int a = 0; a < 8; ++a) {
            float ssum = ba[a0 + a];
            #pragma unroll
            for (int c4 = 0; c4 < 4; ++c4)
                ssum += P[(c4 * A_DIM + a0 + a) * 64 + qi];
            o[a] = fmaxf(ssum, 0.0f);
        }
        float4* op4 = (float4*)(out + ((size_t)b * NPTS + chunk * 64 + qi) * A_DIM + a0);
        op4[0] = make_float4(o[0], o[1], o[2], o[3]);
        op4[1] = make_float4(o[4], o[5], o[6], o[7]);
    }
#undef CAND_D2
#undef PUBLISH
#undef MERGE_FROM
}

extern "C" void kernel_launch(void* const* d_in, const int* in_sizes, int n_in,
                              void* d_out, int out_size, void* d_ws, size_t ws_size,
                              hipStream_t stream) {
    const float* pos  = (const float*)d_in[0];
    const float* goal = (const float*)d_in[1];
    const float* W1   = (const float*)d_in[2];
    const float* b1   = (const float*)d_in[3];
    const float* W2   = (const float*)d_in[4];
    const float* b2   = (const float*)d_in[5];
    const float* Wg   = (const float*)d_in[6];
    const float* bg   = (const float*)d_in[7];
    const float* Wb   = (const float*)d_in[8];
    const float* bb   = (const float*)d_in[9];
    const float* Wa   = (const float*)d_in[10];
    const float* ba   = (const float*)d_in[11];
    float* out = (float*)d_out;

    const int B = in_sizes[0] / (NPTS * 3);
    dim3 grid(B * 64);
    dim3 block(256);
    hipLaunchKernelGGL(knn_film_mlp_kernel, grid, block, 0, stream,
                       pos, goal, W1, b1, W2, b2, Wg, bg, Wb, bb, Wa, ba, out);
}